// Round 3
// baseline (272.536 us; speedup 1.0000x reference)
//
#include <hip/hip_runtime.h>
#include <hip/hip_bf16.h>

// Problem constants
#define B_   2
#define S_   2048
#define D_   1024
#define H_   16
#define DK_  64

typedef unsigned short u16;
typedef __attribute__((ext_vector_type(8))) short bf16x8;   // 8 bf16 = 4 VGPRs (MFMA A/B frag)
typedef __attribute__((ext_vector_type(4))) float f32x4;    // MFMA C/D frag

// log2(e)/8 folded into q-projection; softmax then uses exp2 directly.
#define QSCALE   0.18033688011112042f
#define SMBIAS  -8.656170245333781f     /* -6 * log2(e) */

static __device__ __forceinline__ u16 f2bf(float f) {
  union { float f; unsigned u; } v; v.f = f;
  unsigned r = v.u + 0x7FFF + ((v.u >> 16) & 1);  // RNE
  return (u16)(r >> 16);
}

// async global->LDS, 16B per lane. LDS dest = wave-uniform base + lane*16.
static __device__ __forceinline__ void gl_lds16(const void* g, void* l) {
  __builtin_amdgcn_global_load_lds(
      (const __attribute__((address_space(1))) void*)g,
      (__attribute__((address_space(3))) void*)l, 16, 0, 0);
}

// ---------------- fp32 -> bf16 convert (batched) ----------------
__global__ void cvt3(const float4* __restrict__ a, const float4* __restrict__ b, const float4* __restrict__ c,
                     ushort4* __restrict__ oa, ushort4* __restrict__ ob, ushort4* __restrict__ oc, int n4) {
  int y = blockIdx.y;
  const float4* in = (y == 0) ? a : (y == 1) ? b : c;
  ushort4* out = (y == 0) ? oa : (y == 1) ? ob : oc;
  int i = blockIdx.x * blockDim.x + threadIdx.x;
  if (i < n4) {
    float4 v = in[i];
    ushort4 r;
    r.x = f2bf(v.x); r.y = f2bf(v.y); r.z = f2bf(v.z); r.w = f2bf(v.w);
    out[i] = r;
  }
}
__global__ void cvt4(const float4* __restrict__ a, const float4* __restrict__ b, const float4* __restrict__ c,
                     const float4* __restrict__ d, ushort4* __restrict__ oa, ushort4* __restrict__ ob,
                     ushort4* __restrict__ oc, ushort4* __restrict__ od, int n4) {
  int y = blockIdx.y;
  const float4* in = (y == 0) ? a : (y == 1) ? b : (y == 2) ? c : d;
  ushort4* out = (y == 0) ? oa : (y == 1) ? ob : (y == 2) ? oc : od;
  int i = blockIdx.x * blockDim.x + threadIdx.x;
  if (i < n4) {
    float4 v = in[i];
    ushort4 r;
    r.x = f2bf(v.x); r.y = f2bf(v.y); r.z = f2bf(v.z); r.w = f2bf(v.w);
    out[i] = r;
  }
}

// ---------------- fused QKV projection GEMM ----------------
// z=0: q = (X@Wq^T+bq) * log2e/8 -> [B,H,S,DK]
// z=1: k -> [B,H,S,DK]
// z=2: vT = (X@Wv^T+bv)^T -> [B,H,DK,S], computed as Wv@X^T so writes coalesce.
__launch_bounds__(256, 2)
__global__ void gemm_qkv(const u16* __restrict__ Xq, const u16* __restrict__ Xk, const u16* __restrict__ Xv,
                         const u16* __restrict__ Wq, const u16* __restrict__ Wk, const u16* __restrict__ Wv,
                         const float* __restrict__ bq, const float* __restrict__ bk, const float* __restrict__ bv,
                         u16* __restrict__ outq, u16* __restrict__ outk, u16* __restrict__ outv) {
  const int z = blockIdx.z;
  const u16* Am; const u16* Bm; int m0, n0;
  if (z == 2) { Am = Wv; Bm = Xv; m0 = blockIdx.x * 128; n0 = blockIdx.y * 128; }
  else if (z == 1) { Am = Xk; Bm = Wk; m0 = blockIdx.y * 128; n0 = blockIdx.x * 128; }
  else { Am = Xq; Bm = Wq; m0 = blockIdx.y * 128; n0 = blockIdx.x * 128; }
  const float* bias = (z == 0) ? bq : (z == 1) ? bk : bv;

  __shared__ __align__(16) u16 As[128 * 32];
  __shared__ __align__(16) u16 Bs[128 * 32];

  const int tid = threadIdx.x, lane = tid & 63, w = tid >> 6;
  const int q = lane >> 4, cl = lane & 15;
  const int wr = w >> 1, wc = w & 1;

  f32x4 acc[4][4] = {};

  for (int k0 = 0; k0 < D_; k0 += 32) {
#pragma unroll
    for (int i = 0; i < 2; ++i) {
      int cb = (i * 4 + w) * 64;
      int ch = cb + lane;
      int row = ch >> 2, ko = (ch & 3) << 3;
      gl_lds16(Am + (size_t)(m0 + row) * D_ + k0 + ko, As + cb * 8);
      gl_lds16(Bm + (size_t)(n0 + row) * D_ + k0 + ko, Bs + cb * 8);
    }
    __syncthreads();

    bf16x8 af[4], bfr[4];
#pragma unroll
    for (int r = 0; r < 4; ++r) af[r]  = *(const bf16x8*)(As + (wr * 64 + r * 16 + cl) * 32 + q * 8);
#pragma unroll
    for (int c = 0; c < 4; ++c) bfr[c] = *(const bf16x8*)(Bs + (wc * 64 + c * 16 + cl) * 32 + q * 8);
#pragma unroll
    for (int r = 0; r < 4; ++r)
#pragma unroll
      for (int c = 0; c < 4; ++c)
        acc[r][c] = __builtin_amdgcn_mfma_f32_16x16x32_bf16(af[r], bfr[c], acc[r][c], 0, 0, 0);
    __syncthreads();
  }

  if (z == 2) {
#pragma unroll
    for (int r = 0; r < 4; ++r) {
#pragma unroll
      for (int rr = 0; rr < 4; ++rr) {
        int j = m0 + wr * 64 + r * 16 + q * 4 + rr;
        float bval = bias[j];
        int hh = j >> 6, dk = j & 63;
#pragma unroll
        for (int c = 0; c < 4; ++c) {
          int n = n0 + wc * 64 + c * 16 + cl;
          int bb = n >> 11, s = n & (S_ - 1);
          outv[((size_t)(bb * H_ + hh) * DK_ + dk) * S_ + s] = f2bf(acc[r][c][rr] + bval);
        }
      }
    }
  } else {
    const float scale = (z == 0) ? QSCALE : 1.0f;
    u16* o = (z == 0) ? outq : outk;
#pragma unroll
    for (int c = 0; c < 4; ++c) {
      int j = n0 + wc * 64 + c * 16 + cl;
      float bval = bias[j];
      int hh = j >> 6, dk = j & 63;
#pragma unroll
      for (int r = 0; r < 4; ++r) {
#pragma unroll
        for (int rr = 0; rr < 4; ++rr) {
          int n = m0 + wr * 64 + r * 16 + q * 4 + rr;
          int bb = n >> 11, s = n & (S_ - 1);
          o[((size_t)(bb * H_ + hh) * S_ + s) * DK_ + dk] = f2bf((acc[r][c][rr] + bval) * scale);
        }
      }
    }
  }
}

// ---------------- flash attention ----------------
// Q-tile 128 (wave owns 32 rows as 2 frags), KV-tile 64, double-buffered KV
// prefetch, single barrier per iteration. Fixed-base softmax in exp2 domain.
__launch_bounds__(256, 3)
__global__ void attn(const u16* __restrict__ qh, const u16* __restrict__ kh,
                     const u16* __restrict__ vt, const int* __restrict__ pad,
                     u16* __restrict__ attn_out) {
  __shared__ __align__(16) u16 Ks[2][64 * 64];
  __shared__ __align__(16) u16 Vs[2][64 * 64];
  __shared__ __align__(16) u16 Ps[4][32 * 72];   // stride 72 kills P read conflicts

  const int tid = threadIdx.x, lane = tid & 63, w = tid >> 6;
  const int q = lane >> 4, cl = lane & 15;
  const int qt = (int)gridDim.x - 1 - (int)blockIdx.x;  // heavy blocks first
  const int qb = qt * 128, h = blockIdx.y, b = blockIdx.z;

  const u16* Q = qh + (size_t)(b * H_ + h) * S_ * DK_;
  const u16* K = kh + (size_t)(b * H_ + h) * S_ * DK_;
  const u16* V = vt + (size_t)(b * H_ + h) * DK_ * S_;
  const int* pm = pad + b * S_;

  const int qr0 = qb + w * 32;
  bf16x8 qf[2][2];
#pragma unroll
  for (int f = 0; f < 2; ++f) {
    qf[f][0] = *(const bf16x8*)(Q + (qr0 + f * 16 + cl) * DK_ + q * 8);
    qf[f][1] = *(const bf16x8*)(Q + (qr0 + f * 16 + cl) * DK_ + 32 + q * 8);
  }

  f32x4 o[2][4] = {};
  float ls[2][4] = {};
  u16* Pw = Ps[w];

  const int nkv = 2 * qt + 2;

  // prologue prefetch: tile 0 -> buf 0
#pragma unroll
  for (int i = 0; i < 2; ++i) {
    int s = (i * 4 + w) * 64 + lane;
    int row = s >> 3;
    int c = (s & 7) ^ (row & 7);
    gl_lds16(K + (size_t)row * DK_ + (c << 3), Ks[0] + (size_t)s * 8);
    gl_lds16(V + (size_t)row * S_ + (c << 3), Vs[0] + (size_t)s * 8);
  }

  for (int it = 0; it < nkv; ++it) {
    const int kb = it << 6;
    const int buf = it & 1;
    __syncthreads();   // drains own vmcnt -> tile `it` resident; readers of buf^1 done

    if (it + 1 < nkv) {
      const int kb2 = (it + 1) << 6;
#pragma unroll
      for (int i = 0; i < 2; ++i) {
        int s = (i * 4 + w) * 64 + lane;
        int row = s >> 3;
        int c = (s & 7) ^ (row & 7);
        gl_lds16(K + (size_t)(kb2 + row) * DK_ + (c << 3), Ks[buf ^ 1] + (size_t)s * 8);
        gl_lds16(V + (size_t)row * S_ + kb2 + (c << 3), Vs[buf ^ 1] + (size_t)s * 8);
      }
    }

    if (kb > qr0 + 31) continue;   // fully-masked wave (wave-uniform): skip compute

    const u16* Kt = Ks[buf];
    const u16* Vt = Vs[buf];

    bf16x8 kf[4][2];
#pragma unroll
    for (int ct = 0; ct < 4; ++ct) {
      int rk = ct * 16 + cl;
      int c0 = q ^ (rk & 7);
      kf[ct][0] = *(const bf16x8*)(Kt + rk * 64 + (c0 << 3));
      kf[ct][1] = *(const bf16x8*)(Kt + rk * 64 + ((c0 ^ 4) << 3));
    }

    float kbv[4];
#pragma unroll
    for (int ct = 0; ct < 4; ++ct)
      kbv[ct] = (pm[kb + ct * 16 + cl] != 0) ? SMBIAS : -3e38f;

    f32x4 sa[2][4];
#pragma unroll
    for (int f = 0; f < 2; ++f)
#pragma unroll
      for (int ct = 0; ct < 4; ++ct) {
        f32x4 zz = {};
        zz = __builtin_amdgcn_mfma_f32_16x16x32_bf16(qf[f][0], kf[ct][0], zz, 0, 0, 0);
        zz = __builtin_amdgcn_mfma_f32_16x16x32_bf16(qf[f][1], kf[ct][1], zz, 0, 0, 0);
        sa[f][ct] = zz;
      }

    const bool needmask = (kb + 63 > qr0);
    if (!needmask) {
#pragma unroll
      for (int f = 0; f < 2; ++f)
#pragma unroll
        for (int ct = 0; ct < 4; ++ct)
#pragma unroll
          for (int rr = 0; rr < 4; ++rr) {
            float p = exp2f(sa[f][ct][rr] + kbv[ct]);
            ls[f][rr] += p;
            Pw[(f * 16 + q * 4 + rr) * 72 + ct * 16 + cl] = f2bf(p);
          }
    } else {
#pragma unroll
      for (int f = 0; f < 2; ++f)
#pragma unroll
        for (int ct = 0; ct < 4; ++ct) {
          int kg = kb + ct * 16 + cl;
#pragma unroll
          for (int rr = 0; rr < 4; ++rr) {
            int qg = qr0 + f * 16 + q * 4 + rr;
            float p = (kg <= qg) ? exp2f(sa[f][ct][rr] + kbv[ct]) : 0.f;
            ls[f][rr] += p;
            Pw[(f * 16 + q * 4 + rr) * 72 + ct * 16 + cl] = f2bf(p);
          }
        }
    }

    bf16x8 vf[4][2];
#pragma unroll
    for (int ct = 0; ct < 4; ++ct) {
      int rv = ct * 16 + cl;
      int c0 = q ^ (rv & 7);
      vf[ct][0] = *(const bf16x8*)(Vt + rv * 64 + (c0 << 3));
      vf[ct][1] = *(const bf16x8*)(Vt + rv * 64 + ((c0 ^ 4) << 3));
    }
#pragma unroll
    for (int f = 0; f < 2; ++f) {
      bf16x8 pf0 = *(const bf16x8*)(Pw + (f * 16 + cl) * 72 + q * 8);
      bf16x8 pf1 = *(const bf16x8*)(Pw + (f * 16 + cl) * 72 + 32 + q * 8);
#pragma unroll
      for (int ct = 0; ct < 4; ++ct) {
        o[f][ct] = __builtin_amdgcn_mfma_f32_16x16x32_bf16(pf0, vf[ct][0], o[f][ct], 0, 0, 0);
        o[f][ct] = __builtin_amdgcn_mfma_f32_16x16x32_bf16(pf1, vf[ct][1], o[f][ct], 0, 0, 0);
      }
    }
  }

  // epilogue
#pragma unroll
  for (int f = 0; f < 2; ++f)
#pragma unroll
    for (int rr = 0; rr < 4; ++rr) {
      float l = ls[f][rr];
      l += __shfl_xor(l, 1, 64);
      l += __shfl_xor(l, 2, 64);
      l += __shfl_xor(l, 4, 64);
      l += __shfl_xor(l, 8, 64);
      float inv = 1.0f / l;
      int qg = qr0 + f * 16 + q * 4 + rr;
      size_t base = (size_t)(b * S_ + qg) * D_ + h * DK_;
#pragma unroll
      for (int ct = 0; ct < 4; ++ct)
        attn_out[base + ct * 16 + cl] = f2bf(o[f][ct][rr] * inv);
    }
}

// ---------------- output projection GEMM (fp32 out) ----------------
__launch_bounds__(256, 2)
__global__ void gemm_out(const u16* __restrict__ A, const u16* __restrict__ W,
                         const float* __restrict__ bias, float* __restrict__ out) {
  __shared__ __align__(16) u16 As[128 * 32];
  __shared__ __align__(16) u16 Bs[128 * 32];

  const int tid = threadIdx.x, lane = tid & 63, w = tid >> 6;
  const int q = lane >> 4, cl = lane & 15;
  const int wr = w >> 1, wc = w & 1;
  const int m0 = blockIdx.y * 128, n0 = blockIdx.x * 128;

  f32x4 acc[4][4] = {};

  for (int k0 = 0; k0 < D_; k0 += 32) {
#pragma unroll
    for (int i = 0; i < 2; ++i) {
      int cb = (i * 4 + w) * 64;
      int ch = cb + lane;
      int row = ch >> 2, ko = (ch & 3) << 3;
      gl_lds16(A + (size_t)(m0 + row) * D_ + k0 + ko, As + cb * 8);
      gl_lds16(W + (size_t)(n0 + row) * D_ + k0 + ko, Bs + cb * 8);
    }
    __syncthreads();

    bf16x8 af[4], bfr[4];
#pragma unroll
    for (int r = 0; r < 4; ++r) af[r]  = *(const bf16x8*)(As + (wr * 64 + r * 16 + cl) * 32 + q * 8);
#pragma unroll
    for (int c = 0; c < 4; ++c) bfr[c] = *(const bf16x8*)(Bs + (wc * 64 + c * 16 + cl) * 32 + q * 8);
#pragma unroll
    for (int r = 0; r < 4; ++r)
#pragma unroll
      for (int c = 0; c < 4; ++c)
        acc[r][c] = __builtin_amdgcn_mfma_f32_16x16x32_bf16(af[r], bfr[c], acc[r][c], 0, 0, 0);
    __syncthreads();
  }

#pragma unroll
  for (int c = 0; c < 4; ++c) {
    int j = n0 + wc * 64 + c * 16 + cl;
    float bval = bias[j];
#pragma unroll
    for (int r = 0; r < 4; ++r) {
#pragma unroll
      for (int rr = 0; rr < 4; ++rr) {
        int n = m0 + wr * 64 + r * 16 + q * 4 + rr;
        out[(size_t)n * D_ + j] = acc[r][c][rr] + bval;
      }
    }
  }
}

extern "C" void kernel_launch(void* const* d_in, const int* in_sizes, int n_in,
                              void* d_out, int out_size, void* d_ws, size_t ws_size,
                              hipStream_t stream) {
  const float* Qf  = (const float*)d_in[0];
  const float* Kf  = (const float*)d_in[1];
  const float* Vf  = (const float*)d_in[2];
  const int*   pad = (const int*)d_in[3];
  // d_in[4] = look_ahead_mask (causal tril) — realized via index compare
  const float* Wqf = (const float*)d_in[5];
  const float* bq  = (const float*)d_in[6];
  const float* Wkf = (const float*)d_in[7];
  const float* bk  = (const float*)d_in[8];
  const float* Wvf = (const float*)d_in[9];
  const float* bv  = (const float*)d_in[10];
  const float* Wof = (const float*)d_in[11];
  const float* bo  = (const float*)d_in[12];

  const size_t BSD = (size_t)B_ * S_ * D_;   // 4,194,304
  const size_t DD  = (size_t)D_ * D_;        // 1,048,576

  char* ws = (char*)d_ws;
  u16* Qb   = (u16*)ws; ws += BSD * 2;
  u16* Kb   = (u16*)ws; ws += BSD * 2;
  u16* Vb   = (u16*)ws; ws += BSD * 2;
  u16* Wqb  = (u16*)ws; ws += DD * 2;
  u16* Wkb  = (u16*)ws; ws += DD * 2;
  u16* Wvb  = (u16*)ws; ws += DD * 2;
  u16* Wob  = (u16*)ws; ws += DD * 2;
  u16* qhd  = (u16*)ws; ws += BSD * 2;
  u16* khd  = (u16*)ws; ws += BSD * 2;
  u16* vtd  = (u16*)ws; ws += BSD * 2;
  u16* attn_o = (u16*)ws; ws += BSD * 2;     // total = 64 MiB

  const int n4 = (int)(BSD / 4);             // 1,048,576
  const int w4 = (int)(DD / 4);              // 262,144
  dim3 gc3(n4 / 256, 3), gc4(w4 / 256, 4);
  cvt3<<<gc3, 256, 0, stream>>>((const float4*)Qf, (const float4*)Kf, (const float4*)Vf,
                                (ushort4*)Qb, (ushort4*)Kb, (ushort4*)Vb, n4);
  cvt4<<<gc4, 256, 0, stream>>>((const float4*)Wqf, (const float4*)Wkf, (const float4*)Wvf, (const float4*)Wof,
                                (ushort4*)Wqb, (ushort4*)Wkb, (ushort4*)Wvb, (ushort4*)Wob, w4);

  dim3 g1(D_ / 128, (B_ * S_) / 128, 3);     // (8, 32, 3); z=2 swaps x<->m
  gemm_qkv<<<g1, 256, 0, stream>>>(Qb, Kb, Vb, Wqb, Wkb, Wvb, bq, bk, bv, qhd, khd, vtd);

  dim3 g2(S_ / 128, H_, B_);                 // (16, 16, 2)
  attn<<<g2, 256, 0, stream>>>(qhd, khd, vtd, pad, attn_o);

  dim3 g3(D_ / 128, (B_ * S_) / 128);        // (8, 32)
  gemm_out<<<g3, 256, 0, stream>>>(attn_o, Wob, bo, (float*)d_out);
}